// Round 4
// baseline (577.970 us; speedup 1.0000x reference)
//
#include <hip/hip_runtime.h>
#include <math.h>

#define PI2 6.283185307179586f

// dims: B=4 T=32 C=64 NHEAD=4 DK=16, modes: kh 24 (0..11,20..31), kw 12, J=288
#define SZ_U  (128ull*64*12*64*2)        // 12,582,912 floats  ws[0..)
#define OFF_X (SZ_U)                     // XYft 9,437,184 floats
#define SZ_Q  (4ull*4*32*288*16*2)       // 4,718,592 floats per tensor
// d_out float offsets (scratch staged in d_out; K5 overwrites everything)
#define DO_WP (4ull*SZ_Q)                // Wpack 9,437,184
#define DO_P  (DO_WP + 9437184ull)       // partial scores 786,432
#define DO_S  (DO_P + 786432ull)         // scores 16,384
#define C0f   5.9604644775390625e-8f     // 2^-24

// ---------------- K0: repack weights -> Wpack[tau][j][ri][i][on] ----------------
__global__ __launch_bounds__(256) void k0_repack(
    const float* __restrict__ wq, const float* __restrict__ wk,
    const float* __restrict__ wvx, const float* __restrict__ wvy,
    float* __restrict__ dout) {
  const float* src = (blockIdx.y==0)?wq:(blockIdx.y==1)?wk:(blockIdx.y==2)?wvx:wvy;
  float* wp = dout + DO_WP;
  int base = (blockIdx.x*256 + threadIdx.x)*4;
  #pragma unroll
  for (int u=0; u<4; ++u) {
    int s4 = base + u;
    int m2 = s4 % 12;  int r1 = s4/12;
    int m1 = r1 % 12;  int r2 = r1/12;
    int o  = r2 % 16;  int r3 = r2/16;
    int i  = r3 & 63;  int r4 = r3 >> 6;
    int ri = r4 & 1;   int p  = r4 >> 1;
    int j  = (p*12 + m1)*12 + m2;
    float4 v = ((const float4*)src)[s4];
    size_t d4 = ((size_t)(blockIdx.y*288 + j)*2 + ri)*1024 + (size_t)i*16 + o;
    ((float4*)wp)[d4] = v;
  }
}

// ---------------- K1a: w-DFT (64 -> 12 modes), twiddle recurrence in regs ----------------
__global__ __launch_bounds__(256) void k1a_dftw(const float* __restrict__ z, float* __restrict__ ws) {
  float* U = ws;  // U[bt][r][kw][c][2]
  int tid = threadIdx.x;
  int c4 = tid & 15, kg = (tid>>4)&3, rsub = tid>>6;
  int bt = blockIdx.x >> 3, rg = blockIdx.x & 7;
  float ck[3], sk[3];
  #pragma unroll
  for (int kk=0; kk<3; ++kk) { float s,c; sincosf((PI2/64.f)*(kg+4*kk), &s, &c); ck[kk]=c; sk[kk]=s; }
  for (int it=0; it<2; ++it) {
    int r = rg*8 + it*4 + rsub;
    const float4* zr = (const float4*)(z + ((size_t)bt*64 + r)*4096) + c4;
    float ar[3][4]={{0}}, ai[3][4]={{0}};
    float tr[3]={1.f,1.f,1.f}, ti[3]={0.f,0.f,0.f};
    #pragma unroll 8
    for (int w=0; w<64; ++w) {
      float4 x = zr[(size_t)w*16];
      #pragma unroll
      for (int kk=0; kk<3; ++kk) {
        ar[kk][0] += x.x*tr[kk]; ai[kk][0] += x.x*ti[kk];
        ar[kk][1] += x.y*tr[kk]; ai[kk][1] += x.y*ti[kk];
        ar[kk][2] += x.z*tr[kk]; ai[kk][2] += x.z*ti[kk];
        ar[kk][3] += x.w*tr[kk]; ai[kk][3] += x.w*ti[kk];
        float nr = tr[kk]*ck[kk] + ti[kk]*sk[kk];   // tw *= e^{-2pi i kw/64}
        float ni = ti[kk]*ck[kk] - tr[kk]*sk[kk];
        tr[kk]=nr; ti[kk]=ni;
      }
    }
    #pragma unroll
    for (int kk=0; kk<3; ++kk) {
      int kw = kg+4*kk;
      float4* up = (float4*)(U + (((size_t)bt*64 + r)*12 + kw)*128 + c4*8);
      up[0] = make_float4(ar[kk][0],ai[kk][0],ar[kk][1],ai[kk][1]);
      up[1] = make_float4(ar[kk][2],ai[kk][2],ar[kk][3],ai[kk][3]);
    }
  }
}

// ---------------- K1b: h-DFT (32 -> 24 modes) ----------------
__global__ __launch_bounds__(256) void k1b_dfth(float* __restrict__ ws) {
  const float* U = ws;
  float* X = ws + OFF_X;                // X[bt][half][j][c][2]
  __shared__ float Et[768*2];           // [h][ki] e^{-2pi i kh h/32}
  __shared__ float Ut[32*192*2];        // [h][col=kw*16+cc][2]
  int tid = threadIdx.x;
  for (int q = tid; q < 768; q += 256) {
    int h = q/24, ki = q%24;
    int kh = ki<12 ? ki : ki+8;
    float s,c; sincosf((PI2/32.f)*((kh*h)&31), &s, &c);
    Et[q*2] = c; Et[q*2+1] = -s;
  }
  int bt = blockIdx.x>>3, half = (blockIdx.x>>2)&1, c0 = (blockIdx.x&3)*16;
  for (int q = tid; q < 6144; q += 256) {
    int h = q/192, col = q%192, kw = col>>4, cc = col&15;
    ((float2*)Ut)[q] = *((const float2*)(U + (((size_t)bt*64 + half*32 + h)*12 + kw)*128) + (c0+cc));
  }
  __syncthreads();
  int k3 = tid>>5, cg = tid&31;
  float vr[3][6]={{0}}, vi[3][6]={{0}};
  for (int h=0; h<32; ++h) {
    float er[3], ei[3];
    #pragma unroll
    for (int a=0;a<3;a++){ int ki=k3*3+a; er[a]=Et[(h*24+ki)*2]; ei[a]=Et[(h*24+ki)*2+1]; }
    #pragma unroll
    for (int k=0;k<6;k++){
      float2 u = *(float2*)&Ut[(h*192 + cg + 32*k)*2];
      #pragma unroll
      for (int a=0;a<3;a++){
        vr[a][k] += u.x*er[a] - u.y*ei[a];
        vi[a][k] += u.y*er[a] + u.x*ei[a];
      }
    }
  }
  #pragma unroll
  for (int a=0;a<3;a++)
    #pragma unroll
    for (int k=0;k<6;k++){
      int col = cg+32*k, kw = col>>4, cc = col&15, ki = k3*3+a, j = ki*12+kw;
      *(float2*)(X + ((size_t)(bt*2+half)*288 + j)*128 + (size_t)(c0+cc)*2) = make_float2(vr[a][k], vi[a][k]);
    }
}

// ---------------- K2: per-mode complex GEMM  Q[bt][o,n] = sum_i X[bt][i]*W[i][o,n] ----------------
// grid (288 j, 4 tau, 2 btc) = 2304 UNIFORM blocks (was 3:1 skew on half).
// Register-prefetch pipeline: W(kh) global->regs issued one phase early, so
// HBM/L2 latency hides under X staging (kh=0) / compute (kh=1). 3 barriers.
// Accumulation order kh0 then kh1, i ascending -> bitwise identical.
__global__ __launch_bounds__(256,3) void k2_wmul(const float* __restrict__ ws, float* __restrict__ dout) {
  const float* X = ws + OFF_X;
  const float* Wp = dout + DO_WP;
  __shared__ float Xs[64*132];   // [btL][c][2], row stride 132 floats (pad 4)
  __shared__ float Ws[32*128];   // half-K: [i32][p][2], p = o+16n
  int j = blockIdx.x, tau = blockIdx.y, btc = blockIdx.z;
  int half = (tau==3) ? 1 : 0;
  int tid = threadIdx.x;
  const float4* wsrc = (const float4*)(Wp + ((size_t)(tau*288 + j))*8192);
  // prefetch W(kh=0) -> regs
  float4 wa0[2], wb0[2];
  #pragma unroll
  for (int u=0;u<2;++u){ wa0[u]=wsrc[tid+256*u]; wb0[u]=wsrc[1024+tid+256*u]; }
  // stage X (full K) while W0 is in flight
  for (int q = tid; q < 2048; q += 256) {
    int btL = q>>5, c4 = q&31;
    float4 v = *((const float4*)(X + ((size_t)((btc*64+btL)*2 + half)*288 + j)*128) + c4);
    *(float4*)&Xs[btL*132 + c4*4] = v;
  }
  // write Ws(kh=0)
  #pragma unroll
  for (int u=0;u<2;++u){
    int q = tid+256*u; int i32 = q>>4, o = q&15;
    float* wd = &Ws[i32*128 + o*2];
    *(float2*)&wd[0]  = make_float2(wa0[u].x, wb0[u].x);
    *(float2*)&wd[32] = make_float2(wa0[u].y, wb0[u].y);
    *(float2*)&wd[64] = make_float2(wa0[u].z, wb0[u].z);
    *(float2*)&wd[96] = make_float2(wa0[u].w, wb0[u].w);
  }
  // prefetch W(kh=1) -> regs; latency hides under compute(kh=0)
  float4 wa1[2], wb1[2];
  #pragma unroll
  for (int u=0;u<2;++u){ wa1[u]=wsrc[512+tid+256*u]; wb1[u]=wsrc[1536+tid+256*u]; }
  int trow = tid>>4, tcol = tid&15;
  float ar[4][4]={{0}}, ai[4][4]={{0}};
  __syncthreads();
  { // compute kh=0
    const float* xb = &Xs[trow*132];
    const float* wb = &Ws[tcol*2];
    #pragma unroll 8
    for (int i=0; i<32; ++i) {
      float xr[4], xi[4], wr[4], wi[4];
      #pragma unroll
      for (int a=0;a<4;a++){
        float2 xv = *(const float2*)&xb[a*2112 + i*2];   // a stride = 16*132
        xr[a]=xv.x; xi[a]=xv.y;
      }
      #pragma unroll
      for (int b=0;b<4;b++){
        float2 wv = *(const float2*)&wb[i*128 + b*32];
        wr[b]=wv.x; wi[b]=wv.y;
      }
      #pragma unroll
      for (int a=0;a<4;a++)
        #pragma unroll
        for (int b=0;b<4;b++){
          ar[a][b] += xr[a]*wr[b] - xi[a]*wi[b];
          ai[a][b] += xr[a]*wi[b] + xi[a]*wr[b];
        }
    }
  }
  __syncthreads();
  // write Ws(kh=1) from regs
  #pragma unroll
  for (int u=0;u<2;++u){
    int q = tid+256*u; int i32 = q>>4, o = q&15;
    float* wd = &Ws[i32*128 + o*2];
    *(float2*)&wd[0]  = make_float2(wa1[u].x, wb1[u].x);
    *(float2*)&wd[32] = make_float2(wa1[u].y, wb1[u].y);
    *(float2*)&wd[64] = make_float2(wa1[u].z, wb1[u].z);
    *(float2*)&wd[96] = make_float2(wa1[u].w, wb1[u].w);
  }
  __syncthreads();
  { // compute kh=1
    const float* xb = &Xs[trow*132 + 64];
    const float* wb = &Ws[tcol*2];
    #pragma unroll 8
    for (int i=0; i<32; ++i) {
      float xr[4], xi[4], wr[4], wi[4];
      #pragma unroll
      for (int a=0;a<4;a++){
        float2 xv = *(const float2*)&xb[a*2112 + i*2];
        xr[a]=xv.x; xi[a]=xv.y;
      }
      #pragma unroll
      for (int b=0;b<4;b++){
        float2 wv = *(const float2*)&wb[i*128 + b*32];
        wr[b]=wv.x; wi[b]=wv.y;
      }
      #pragma unroll
      for (int a=0;a<4;a++)
        #pragma unroll
        for (int b=0;b<4;b++){
          ar[a][b] += xr[a]*wr[b] - xi[a]*wi[b];
          ai[a][b] += xr[a]*wi[b] + xi[a]*wr[b];
        }
    }
  }
  float* obase = dout + (size_t)tau*SZ_Q;
  #pragma unroll
  for (int a=0;a<4;a++){
    int bt = btc*64 + trow + 16*a;
    int b_ = bt>>5, t = bt&31;
    #pragma unroll
    for (int bb=0;bb<4;bb++){
      int o = tcol, n = bb;   // lane-contiguous 128B per (row) chunk
      *(float2*)(obase + ((((size_t)(b_*4+n)*32 + t)*288 + j)*16 + o)*2) = make_float2(ar[a][bb], ai[a][bb]);
    }
  }
}

// ---------------- K3: partial scores in mode space (Gram with kw=0 conj-partner fix) ----------------
__global__ __launch_bounds__(256) void k3_scores(float* __restrict__ dout) {
  const float* Q = dout;
  const float* K = dout + SZ_Q;
  float* P = dout + DO_P;
  __shared__ float lds[12544];
  float* Qs = lds;            // 32 rows * 196
  float* Ks = lds + 6272;
  int jc = blockIdx.x, bn = blockIdx.y;
  int tid = threadIdx.x;
  for (int q = tid; q < 1536; q += 256) {
    int t = q/48, f4 = q%48;
    *(float4*)&Qs[t*196 + f4*4] = *((const float4*)(Q + (size_t)(bn*32+t)*9216 + jc*192) + f4);
  }
  for (int q = tid; q < 1536; q += 256) {
    int s = q/48, f4 = q%48;
    int kw = (jc*6 + (f4>>3)) % 12;
    float w1 = (kw==0) ? C0f : 4.f*C0f;
    float4 v = *((const float4*)(K + (size_t)(bn*32+s)*9216 + jc*192) + f4);
    v.x*=w1; v.y*=w1; v.z*=w1; v.w*=w1;
    *(float4*)&Ks[s*196 + f4*4] = v;
  }
  __syncthreads();
  if (((jc&1)==0) && ((jc>>1)!=12)) {           // kw==0 column lives at local j 0 when jc even
    int khI = jc>>1;
    int jp = ((24 - khI) % 24) * 12;            // conjugate partner mode
    for (int q = tid; q < 512; q += 256) {
      int s = q>>4, d = q&15;
      float2 kp = *((const float2*)(K + (size_t)(bn*32+s)*9216 + (size_t)jp*32) + d);
      Ks[s*196 + d*2]     += C0f * kp.x;
      Ks[s*196 + d*2 + 1] -= C0f * kp.y;
    }
  }
  __syncthreads();
  int tq = tid>>5, sq = (tid>>2)&7, eg = tid&3;
  float acc[4][4]={{0}};
  for (int e=0; e<12; ++e) {
    float4 qv[4], kv[4];
    #pragma unroll
    for (int a=0;a<4;a++) qv[a] = *(float4*)&Qs[(tq*4+a)*196 + eg*48 + e*4];
    #pragma unroll
    for (int b=0;b<4;b++) kv[b] = *(float4*)&Ks[(sq*4+b)*196 + eg*48 + e*4];
    #pragma unroll
    for (int a=0;a<4;a++)
      #pragma unroll
      for (int b=0;b<4;b++)
        acc[a][b] += qv[a].x*kv[b].x + qv[a].y*kv[b].y + qv[a].z*kv[b].z + qv[a].w*kv[b].w;
  }
  __syncthreads();
  float* Pp = lds;            // alias (Qs dead)
  #pragma unroll
  for (int a=0;a<4;a++)
    #pragma unroll
    for (int b=0;b<4;b++)
      Pp[eg*1056 + (tq*4+a)*33 + (sq*4+b)] = acc[a][b];
  __syncthreads();
  for (int q = tid; q < 1024; q += 256) {
    int t = q>>5, s = q&31;
    float r = Pp[t*33+s] + Pp[1056 + t*33+s] + Pp[2112 + t*33+s] + Pp[3168 + t*33+s];
    P[(size_t)(jc*16 + bn)*1024 + q] = r;
  }
}

__global__ __launch_bounds__(256) void k3b_reduce(float* __restrict__ dout) {
  const float* P = dout + DO_P;
  float* S = dout + DO_S;
  int bn = blockIdx.x, tid = threadIdx.x;
  for (int q = tid; q < 1024; q += 256) {
    float a = 0.f;
    for (int jc=0; jc<48; ++jc) a += P[(size_t)(jc*16+bn)*1024 + q];
    S[bn*1024 + q] = a;
  }
}

// ---------------- K4: mode-space score mixing  O[t] = sum_s S[t][s] V[s] ----------------
__global__ __launch_bounds__(256) void k4_mix(const float* __restrict__ dout, float* __restrict__ ws) {
  const float* S = dout + DO_S;
  const float* V = dout + (blockIdx.z==0 ? 2ull*SZ_Q : 3ull*SZ_Q);
  float* O = ws + (blockIdx.z==0 ? 0ull : SZ_Q);    // aliases dead U region
  __shared__ float scs[1056];
  __shared__ float Vs[32*388];
  int jc = blockIdx.x, bn = blockIdx.y, tid = threadIdx.x;
  for (int q = tid; q < 1024; q += 256) scs[(q>>5)*33 + (q&31)] = S[bn*1024 + q];
  for (int q = tid; q < 3072; q += 256) {
    int s = q/96, f4 = q%96;
    *(float4*)&Vs[s*388 + f4*4] = *((const float4*)(V + (size_t)(bn*32+s)*9216 + jc*384) + f4);
  }
  __syncthreads();
  int tq = tid>>5, ec = tid&31;
  float4 acc[4][3];
  #pragma unroll
  for (int a=0;a<4;a++)
    #pragma unroll
    for (int c=0;c<3;c++) acc[a][c] = make_float4(0.f,0.f,0.f,0.f);
  for (int s=0; s<32; ++s) {
    float sc[4];
    #pragma unroll
    for (int a=0;a<4;a++) sc[a] = scs[(tq*4+a)*33 + s];
    #pragma unroll
    for (int cc=0;cc<3;cc++){
      float4 v = *(float4*)&Vs[s*388 + (ec+32*cc)*4];
      #pragma unroll
      for (int a=0;a<4;a++){
        acc[a][cc].x += sc[a]*v.x; acc[a][cc].y += sc[a]*v.y;
        acc[a][cc].z += sc[a]*v.z; acc[a][cc].w += sc[a]*v.w;
      }
    }
  }
  #pragma unroll
  for (int a=0;a<4;a++)
    #pragma unroll
    for (int cc=0;cc<3;cc++)
      *((float4*)(O + (size_t)(bn*32 + tq*4+a)*9216 + jc*384) + (ec+32*cc)) = acc[a][cc];
}

// ---------------- K5: inverse DFT + gauss + write out ----------------
// grid (idx, half, rnd): 2048 blocks, 512 thr. Fs read direct from global
// (per-wave 512B contiguous, 8x reuse via L1/L2). LDS 24.8KB -> 4 blocks/CU.
__global__ __launch_bounds__(512) void k5_out(const float* __restrict__ ws, float* __restrict__ dout) {
  __shared__ float Cs[6144];     // [hl(16)][col(192)][2], wgt/2048 folded
  __shared__ float gt[64];       // unnormalized gaussian
  int tid = threadIdx.x;
  int idx  = blockIdx.x;         // bn*32 + t
  int half = blockIdx.y;
  int rnd  = blockIdx.z;
  if (tid < 64) { float dr = tid - 31.5f; gt[tid] = expf(-0.02f*dr*dr); }
  __syncthreads();
  float gsum = 0.f;
  for (int i=0;i<64;i++) gsum += gt[i];    // same order as before -> same rounding
  const float* src = ws + (half ? SZ_Q : 0ull) + (size_t)idx*9216;
  { // stage A: kh-sum for 16 h rows, e^{+2pi i kh h/32} via recurrence
    int h2 = tid>>6, cg = tid&63;
    int h0 = rnd*16 + h2*2, h1 = h0+1;
    float s0,c0s,s1,c1s;
    sincosf((PI2/32.f)*h0, &s0, &c0s);
    sincosf((PI2/32.f)*h1, &s1, &c1s);
    float e0r=1.f, e0i=0.f, e1r=1.f, e1i=0.f;
    float a0r[3]={0},a0i[3]={0},a1r[3]={0},a1i[3]={0};
    const float2* sp = (const float2*)src;
    for (int ki=0; ki<24; ++ki) {
      if (ki==12) {
        float s,c;
        sincosf((PI2/32.f)*((20*h0)&31), &s, &c); e0r=c; e0i=s;
        sincosf((PI2/32.f)*((20*h1)&31), &s, &c); e1r=c; e1i=s;
      }
      #pragma unroll
      for (int k=0;k<3;k++){
        float2 f = sp[ki*192 + cg + 64*k];
        a0r[k] += f.x*e0r - f.y*e0i;  a0i[k] += f.x*e0i + f.y*e0r;
        a1r[k] += f.x*e1r - f.y*e1i;  a1i[k] += f.x*e1i + f.y*e1r;
      }
      float n0r = e0r*c0s - e0i*s0, n0i = e0r*s0 + e0i*c0s; e0r=n0r; e0i=n0i;
      float n1r = e1r*c1s - e1i*s1, n1i = e1r*s1 + e1i*c1s; e1r=n1r; e1i=n1i;
    }
    #pragma unroll
    for (int k=0;k<3;k++){
      int col = cg+64*k, kw = col>>4;
      float sc = (kw==0 ? 1.f : 2.f) * (1.f/2048.f);
      int base0 = (h2*2*192 + col)*2;
      Cs[base0]     = a0r[k]*sc; Cs[base0+1]   = a0i[k]*sc;
      Cs[base0+384] = a1r[k]*sc; Cs[base0+385] = a1i[k]*sc;
    }
  }
  __syncthreads();
  { // stage B: kw-sum over w with phi recurrence, gauss, store
    int hl = tid>>5, wg = (tid>>2)&7, dq = tid&3;
    float cr[12][4], ci[12][4];
    #pragma unroll
    for (int kw=0;kw<12;kw++){
      float4 u = *(float4*)&Cs[hl*384 + kw*32 + dq*8];
      float4 v = *(float4*)&Cs[hl*384 + kw*32 + dq*8 + 4];
      cr[kw][0]=u.x; ci[kw][0]=u.y; cr[kw][1]=u.z; ci[kw][1]=u.w;
      cr[kw][2]=v.x; ci[kw][2]=v.y; cr[kw][3]=v.z; ci[kw][3]=v.w;
    }
    int row = half*32 + rnd*16 + hl;
    float grow = gt[row]/gsum;          // == normalized gt[row] (same rounding)
    float pr, pi;
    sincosf((PI2/64.f)*wg, &pi, &pr);   // phi = e^{2pi i w/64}
    float* ob = dout + (size_t)idx*65536 + (size_t)row*1024;
    for (int k=0;k<8;k++){
      int w = wg + 8*k;
      float v0=cr[0][0], v1=cr[0][1], v2=cr[0][2], v3=cr[0][3];
      float tr=pr, ti=pi;
      #pragma unroll
      for (int kw=1;kw<12;kw++){
        v0 += cr[kw][0]*tr - ci[kw][0]*ti;
        v1 += cr[kw][1]*tr - ci[kw][1]*ti;
        v2 += cr[kw][2]*tr - ci[kw][2]*ti;
        v3 += cr[kw][3]*tr - ci[kw][3]*ti;
        float nr = tr*pr - ti*pi, ni = tr*pi + ti*pr;
        tr=nr; ti=ni;
      }
      float g = grow * (gt[w]/gsum);    // == grow * normalized gt[w]
      *(float4*)(ob + w*16 + dq*4) = make_float4(v0*g, v1*g, v2*g, v3*g);
      float nr = (pr - pi)*0.70710678118654752f;  // phi *= e^{i pi/4}  (w += 8)
      float ni = (pr + pi)*0.70710678118654752f;
      pr=nr; pi=ni;
    }
  }
}

extern "C" void kernel_launch(void* const* d_in, const int* in_sizes, int n_in,
                              void* d_out, int out_size, void* d_ws, size_t ws_size,
                              hipStream_t stream) {
  const float* z   = (const float*)d_in[0];
  const float* wq  = (const float*)d_in[1];
  const float* wk  = (const float*)d_in[2];
  const float* wvx = (const float*)d_in[3];
  const float* wvy = (const float*)d_in[4];
  float* out = (float*)d_out;
  float* ws  = (float*)d_ws;
  hipLaunchKernelGGL(k0_repack, dim3(576,4), dim3(256), 0, stream, wq, wk, wvx, wvy, out);
  hipLaunchKernelGGL(k1a_dftw,  dim3(1024),  dim3(256), 0, stream, z, ws);
  hipLaunchKernelGGL(k1b_dfth,  dim3(1024),  dim3(256), 0, stream, ws);
  hipLaunchKernelGGL(k2_wmul,   dim3(288,4,2), dim3(256), 0, stream, ws, out);
  hipLaunchKernelGGL(k3_scores, dim3(48,16), dim3(256), 0, stream, out);
  hipLaunchKernelGGL(k3b_reduce,dim3(16),    dim3(256), 0, stream, out);
  hipLaunchKernelGGL(k4_mix,    dim3(24,16,2), dim3(256), 0, stream, out, ws);
  hipLaunchKernelGGL(k5_out,    dim3(512,2,2), dim3(512), 0, stream, ws, out);
}

// Round 5
// 546.562 us; speedup vs baseline: 1.0575x; 1.0575x over previous
//
#include <hip/hip_runtime.h>
#include <math.h>

#define PI2 6.283185307179586f

typedef float f2v __attribute__((ext_vector_type(2)));

// dims: B=4 T=32 C=64 NHEAD=4 DK=16, modes: kh 24 (0..11,20..31), kw 12, J=288
#define SZ_U  (128ull*64*12*64*2)        // 12,582,912 floats  ws[0..)
#define OFF_X (SZ_U)                     // XYft 9,437,184 floats
#define SZ_Q  (4ull*4*32*288*16*2)       // 4,718,592 floats per tensor
// d_out float offsets (scratch staged in d_out; K5 overwrites everything)
#define DO_WP (4ull*SZ_Q)                // Wpack 9,437,184
#define DO_P  (DO_WP + 9437184ull)       // partial scores 786,432
#define DO_S  (DO_P + 786432ull)         // scores 16,384
#define C0f   5.9604644775390625e-8f     // 2^-24

// ---------------- K0: repack weights -> Wpack[tau][j][ri][i][on] ----------------
__global__ __launch_bounds__(256) void k0_repack(
    const float* __restrict__ wq, const float* __restrict__ wk,
    const float* __restrict__ wvx, const float* __restrict__ wvy,
    float* __restrict__ dout) {
  const float* src = (blockIdx.y==0)?wq:(blockIdx.y==1)?wk:(blockIdx.y==2)?wvx:wvy;
  float* wp = dout + DO_WP;
  int base = (blockIdx.x*256 + threadIdx.x)*4;
  #pragma unroll
  for (int u=0; u<4; ++u) {
    int s4 = base + u;
    int m2 = s4 % 12;  int r1 = s4/12;
    int m1 = r1 % 12;  int r2 = r1/12;
    int o  = r2 % 16;  int r3 = r2/16;
    int i  = r3 & 63;  int r4 = r3 >> 6;
    int ri = r4 & 1;   int p  = r4 >> 1;
    int j  = (p*12 + m1)*12 + m2;
    float4 v = ((const float4*)src)[s4];
    size_t d4 = ((size_t)(blockIdx.y*288 + j)*2 + ri)*1024 + (size_t)i*16 + o;
    ((float4*)wp)[d4] = v;
  }
}

// ---------------- K1a: w-DFT (64 -> 12 modes), twiddle recurrence in regs ----------------
__global__ __launch_bounds__(256) void k1a_dftw(const float* __restrict__ z, float* __restrict__ ws) {
  float* U = ws;  // U[bt][r][kw][c][2]
  int tid = threadIdx.x;
  int c4 = tid & 15, kg = (tid>>4)&3, rsub = tid>>6;
  int bt = blockIdx.x >> 3, rg = blockIdx.x & 7;
  float ck[3], sk[3];
  #pragma unroll
  for (int kk=0; kk<3; ++kk) { float s,c; sincosf((PI2/64.f)*(kg+4*kk), &s, &c); ck[kk]=c; sk[kk]=s; }
  for (int it=0; it<2; ++it) {
    int r = rg*8 + it*4 + rsub;
    const float4* zr = (const float4*)(z + ((size_t)bt*64 + r)*4096) + c4;
    float ar[3][4]={{0}}, ai[3][4]={{0}};
    float tr[3]={1.f,1.f,1.f}, ti[3]={0.f,0.f,0.f};
    #pragma unroll 8
    for (int w=0; w<64; ++w) {
      float4 x = zr[(size_t)w*16];
      #pragma unroll
      for (int kk=0; kk<3; ++kk) {
        ar[kk][0] += x.x*tr[kk]; ai[kk][0] += x.x*ti[kk];
        ar[kk][1] += x.y*tr[kk]; ai[kk][1] += x.y*ti[kk];
        ar[kk][2] += x.z*tr[kk]; ai[kk][2] += x.z*ti[kk];
        ar[kk][3] += x.w*tr[kk]; ai[kk][3] += x.w*ti[kk];
        float nr = tr[kk]*ck[kk] + ti[kk]*sk[kk];   // tw *= e^{-2pi i kw/64}
        float ni = ti[kk]*ck[kk] - tr[kk]*sk[kk];
        tr[kk]=nr; ti[kk]=ni;
      }
    }
    #pragma unroll
    for (int kk=0; kk<3; ++kk) {
      int kw = kg+4*kk;
      float4* up = (float4*)(U + (((size_t)bt*64 + r)*12 + kw)*128 + c4*8);
      up[0] = make_float4(ar[kk][0],ai[kk][0],ar[kk][1],ai[kk][1]);
      up[1] = make_float4(ar[kk][2],ai[kk][2],ar[kk][3],ai[kk][3]);
    }
  }
}

// ---------------- K1b: h-DFT (32 -> 24 modes) ----------------
__global__ __launch_bounds__(256) void k1b_dfth(float* __restrict__ ws) {
  const float* U = ws;
  float* X = ws + OFF_X;                // X[bt][half][j][c][2]
  __shared__ float Et[768*2];           // [h][ki] e^{-2pi i kh h/32}
  __shared__ float Ut[32*192*2];        // [h][col=kw*16+cc][2]
  int tid = threadIdx.x;
  for (int q = tid; q < 768; q += 256) {
    int h = q/24, ki = q%24;
    int kh = ki<12 ? ki : ki+8;
    float s,c; sincosf((PI2/32.f)*((kh*h)&31), &s, &c);
    Et[q*2] = c; Et[q*2+1] = -s;
  }
  int bt = blockIdx.x>>3, half = (blockIdx.x>>2)&1, c0 = (blockIdx.x&3)*16;
  for (int q = tid; q < 6144; q += 256) {
    int h = q/192, col = q%192, kw = col>>4, cc = col&15;
    ((float2*)Ut)[q] = *((const float2*)(U + (((size_t)bt*64 + half*32 + h)*12 + kw)*128) + (c0+cc));
  }
  __syncthreads();
  int k3 = tid>>5, cg = tid&31;
  float vr[3][6]={{0}}, vi[3][6]={{0}};
  for (int h=0; h<32; ++h) {
    float er[3], ei[3];
    #pragma unroll
    for (int a=0;a<3;a++){ int ki=k3*3+a; er[a]=Et[(h*24+ki)*2]; ei[a]=Et[(h*24+ki)*2+1]; }
    #pragma unroll
    for (int k=0;k<6;k++){
      float2 u = *(float2*)&Ut[(h*192 + cg + 32*k)*2];
      #pragma unroll
      for (int a=0;a<3;a++){
        vr[a][k] += u.x*er[a] - u.y*ei[a];
        vi[a][k] += u.y*er[a] + u.x*ei[a];
      }
    }
  }
  #pragma unroll
  for (int a=0;a<3;a++)
    #pragma unroll
    for (int k=0;k<6;k++){
      int col = cg+32*k, kw = col>>4, cc = col&15, ki = k3*3+a, j = ki*12+kw;
      *(float2*)(X + ((size_t)(bt*2+half)*288 + j)*128 + (size_t)(c0+cc)*2) = make_float2(vr[a][k], vi[a][k]);
    }
}

// ---------------- K2: per-mode complex GEMM  Q[bt][o,n] = sum_i X[bt][i]*W[i][o,n] ----------------
// grid (288 j, 4 tau, 2 btc) = 2304 uniform blocks, reg-prefetch pipeline.
// Inner loop: packed complex MAC via v_pk_fma_f32 (ext_vector f2v):
//   acc{ar,ai} += {xr,xr}*{wr,wi};  acc += {-xi,xi}*{wi,wr}
// Same per-element fma ops, i-ascending order preserved.
__global__ __launch_bounds__(256,3) void k2_wmul(const float* __restrict__ ws, float* __restrict__ dout) {
  const float* X = ws + OFF_X;
  const float* Wp = dout + DO_WP;
  __shared__ float Xs[64*132];   // [btL][c][2], row stride 132 floats (pad 4)
  __shared__ float Ws[32*128];   // half-K: [i32][p][2], p = o+16n
  int j = blockIdx.x, tau = blockIdx.y, btc = blockIdx.z;
  int half = (tau==3) ? 1 : 0;
  int tid = threadIdx.x;
  const float4* wsrc = (const float4*)(Wp + ((size_t)(tau*288 + j))*8192);
  // prefetch W(kh=0) -> regs
  float4 wa0[2], wb0[2];
  #pragma unroll
  for (int u=0;u<2;++u){ wa0[u]=wsrc[tid+256*u]; wb0[u]=wsrc[1024+tid+256*u]; }
  // stage X (full K) while W0 is in flight
  for (int q = tid; q < 2048; q += 256) {
    int btL = q>>5, c4 = q&31;
    float4 v = *((const float4*)(X + ((size_t)((btc*64+btL)*2 + half)*288 + j)*128) + c4);
    *(float4*)&Xs[btL*132 + c4*4] = v;
  }
  // write Ws(kh=0)
  #pragma unroll
  for (int u=0;u<2;++u){
    int q = tid+256*u; int i32 = q>>4, o = q&15;
    float* wd = &Ws[i32*128 + o*2];
    *(float2*)&wd[0]  = make_float2(wa0[u].x, wb0[u].x);
    *(float2*)&wd[32] = make_float2(wa0[u].y, wb0[u].y);
    *(float2*)&wd[64] = make_float2(wa0[u].z, wb0[u].z);
    *(float2*)&wd[96] = make_float2(wa0[u].w, wb0[u].w);
  }
  // prefetch W(kh=1) -> regs; latency hides under compute(kh=0)
  float4 wa1[2], wb1[2];
  #pragma unroll
  for (int u=0;u<2;++u){ wa1[u]=wsrc[512+tid+256*u]; wb1[u]=wsrc[1536+tid+256*u]; }
  int trow = tid>>4, tcol = tid&15;
  f2v acc[4][4];
  #pragma unroll
  for (int a=0;a<4;a++)
    #pragma unroll
    for (int b=0;b<4;b++) acc[a][b] = (f2v){0.f, 0.f};
  __syncthreads();
  { // compute kh=0
    const float* xb = &Xs[trow*132];
    const f2v*  wb2 = (const f2v*)&Ws[tcol*2];   // wb2[i*64 + b*16]
    #pragma unroll 8
    for (int ip=0; ip<16; ++ip) {
      float4 xq[4];
      #pragma unroll
      for (int a=0;a<4;a++) xq[a] = *(const float4*)&xb[a*2112 + ip*4];
      f2v wp0[4], wp1[4];
      #pragma unroll
      for (int b=0;b<4;b++){ wp0[b] = wb2[(2*ip)*64 + b*16]; wp1[b] = wb2[(2*ip+1)*64 + b*16]; }
      #pragma unroll
      for (int a=0;a<4;a++){
        f2v xr0 = (f2v){ xq[a].x, xq[a].x};
        f2v xi0 = (f2v){-xq[a].y, xq[a].y};
        f2v xr1 = (f2v){ xq[a].z, xq[a].z};
        f2v xi1 = (f2v){-xq[a].w, xq[a].w};
        #pragma unroll
        for (int b=0;b<4;b++){
          acc[a][b] = __builtin_elementwise_fma(xr0, wp0[b],    acc[a][b]);
          acc[a][b] = __builtin_elementwise_fma(xi0, wp0[b].yx, acc[a][b]);
          acc[a][b] = __builtin_elementwise_fma(xr1, wp1[b],    acc[a][b]);
          acc[a][b] = __builtin_elementwise_fma(xi1, wp1[b].yx, acc[a][b]);
        }
      }
    }
  }
  __syncthreads();
  // write Ws(kh=1) from regs
  #pragma unroll
  for (int u=0;u<2;++u){
    int q = tid+256*u; int i32 = q>>4, o = q&15;
    float* wd = &Ws[i32*128 + o*2];
    *(float2*)&wd[0]  = make_float2(wa1[u].x, wb1[u].x);
    *(float2*)&wd[32] = make_float2(wa1[u].y, wb1[u].y);
    *(float2*)&wd[64] = make_float2(wa1[u].z, wb1[u].z);
    *(float2*)&wd[96] = make_float2(wa1[u].w, wb1[u].w);
  }
  __syncthreads();
  { // compute kh=1
    const float* xb = &Xs[trow*132 + 64];
    const f2v*  wb2 = (const f2v*)&Ws[tcol*2];
    #pragma unroll 8
    for (int ip=0; ip<16; ++ip) {
      float4 xq[4];
      #pragma unroll
      for (int a=0;a<4;a++) xq[a] = *(const float4*)&xb[a*2112 + ip*4];
      f2v wp0[4], wp1[4];
      #pragma unroll
      for (int b=0;b<4;b++){ wp0[b] = wb2[(2*ip)*64 + b*16]; wp1[b] = wb2[(2*ip+1)*64 + b*16]; }
      #pragma unroll
      for (int a=0;a<4;a++){
        f2v xr0 = (f2v){ xq[a].x, xq[a].x};
        f2v xi0 = (f2v){-xq[a].y, xq[a].y};
        f2v xr1 = (f2v){ xq[a].z, xq[a].z};
        f2v xi1 = (f2v){-xq[a].w, xq[a].w};
        #pragma unroll
        for (int b=0;b<4;b++){
          acc[a][b] = __builtin_elementwise_fma(xr0, wp0[b],    acc[a][b]);
          acc[a][b] = __builtin_elementwise_fma(xi0, wp0[b].yx, acc[a][b]);
          acc[a][b] = __builtin_elementwise_fma(xr1, wp1[b],    acc[a][b]);
          acc[a][b] = __builtin_elementwise_fma(xi1, wp1[b].yx, acc[a][b]);
        }
      }
    }
  }
  float* obase = dout + (size_t)tau*SZ_Q;
  #pragma unroll
  for (int a=0;a<4;a++){
    int bt = btc*64 + trow + 16*a;
    int b_ = bt>>5, t = bt&31;
    #pragma unroll
    for (int bb=0;bb<4;bb++){
      int o = tcol, n = bb;   // lane-contiguous 128B per (row) chunk
      *(f2v*)(obase + ((((size_t)(b_*4+n)*32 + t)*288 + j)*16 + o)*2) = acc[a][bb];
    }
  }
}

// ---------------- K3: partial scores in mode space (Gram with kw=0 conj-partner fix) ----------------
__global__ __launch_bounds__(256) void k3_scores(float* __restrict__ dout) {
  const float* Q = dout;
  const float* K = dout + SZ_Q;
  float* P = dout + DO_P;
  __shared__ float lds[12544];
  float* Qs = lds;            // 32 rows * 196
  float* Ks = lds + 6272;
  int jc = blockIdx.x, bn = blockIdx.y;
  int tid = threadIdx.x;
  for (int q = tid; q < 1536; q += 256) {
    int t = q/48, f4 = q%48;
    *(float4*)&Qs[t*196 + f4*4] = *((const float4*)(Q + (size_t)(bn*32+t)*9216 + jc*192) + f4);
  }
  for (int q = tid; q < 1536; q += 256) {
    int s = q/48, f4 = q%48;
    int kw = (jc*6 + (f4>>3)) % 12;
    float w1 = (kw==0) ? C0f : 4.f*C0f;
    float4 v = *((const float4*)(K + (size_t)(bn*32+s)*9216 + jc*192) + f4);
    v.x*=w1; v.y*=w1; v.z*=w1; v.w*=w1;
    *(float4*)&Ks[s*196 + f4*4] = v;
  }
  __syncthreads();
  if (((jc&1)==0) && ((jc>>1)!=12)) {           // kw==0 column lives at local j 0 when jc even
    int khI = jc>>1;
    int jp = ((24 - khI) % 24) * 12;            // conjugate partner mode
    for (int q = tid; q < 512; q += 256) {
      int s = q>>4, d = q&15;
      float2 kp = *((const float2*)(K + (size_t)(bn*32+s)*9216 + (size_t)jp*32) + d);
      Ks[s*196 + d*2]     += C0f * kp.x;
      Ks[s*196 + d*2 + 1] -= C0f * kp.y;
    }
  }
  __syncthreads();
  int tq = tid>>5, sq = (tid>>2)&7, eg = tid&3;
  float acc[4][4]={{0}};
  for (int e=0; e<12; ++e) {
    float4 qv[4], kv[4];
    #pragma unroll
    for (int a=0;a<4;a++) qv[a] = *(float4*)&Qs[(tq*4+a)*196 + eg*48 + e*4];
    #pragma unroll
    for (int b=0;b<4;b++) kv[b] = *(float4*)&Ks[(sq*4+b)*196 + eg*48 + e*4];
    #pragma unroll
    for (int a=0;a<4;a++)
      #pragma unroll
      for (int b=0;b<4;b++)
        acc[a][b] += qv[a].x*kv[b].x + qv[a].y*kv[b].y + qv[a].z*kv[b].z + qv[a].w*kv[b].w;
  }
  __syncthreads();
  float* Pp = lds;            // alias (Qs dead)
  #pragma unroll
  for (int a=0;a<4;a++)
    #pragma unroll
    for (int b=0;b<4;b++)
      Pp[eg*1056 + (tq*4+a)*33 + (sq*4+b)] = acc[a][b];
  __syncthreads();
  for (int q = tid; q < 1024; q += 256) {
    int t = q>>5, s = q&31;
    float r = Pp[t*33+s] + Pp[1056 + t*33+s] + Pp[2112 + t*33+s] + Pp[3168 + t*33+s];
    P[(size_t)(jc*16 + bn)*1024 + q] = r;
  }
}

__global__ __launch_bounds__(256) void k3b_reduce(float* __restrict__ dout) {
  const float* P = dout + DO_P;
  float* S = dout + DO_S;
  int bn = blockIdx.x, tid = threadIdx.x;
  for (int q = tid; q < 1024; q += 256) {
    float a = 0.f;
    for (int jc=0; jc<48; ++jc) a += P[(size_t)(jc*16+bn)*1024 + q];
    S[bn*1024 + q] = a;
  }
}

// ---------------- K4: mode-space score mixing  O[t] = sum_s S[t][s] V[s] ----------------
__global__ __launch_bounds__(256) void k4_mix(const float* __restrict__ dout, float* __restrict__ ws) {
  const float* S = dout + DO_S;
  const float* V = dout + (blockIdx.z==0 ? 2ull*SZ_Q : 3ull*SZ_Q);
  float* O = ws + (blockIdx.z==0 ? 0ull : SZ_Q);    // aliases dead U region
  __shared__ float scs[1056];
  __shared__ float Vs[32*388];
  int jc = blockIdx.x, bn = blockIdx.y, tid = threadIdx.x;
  for (int q = tid; q < 1024; q += 256) scs[(q>>5)*33 + (q&31)] = S[bn*1024 + q];
  for (int q = tid; q < 3072; q += 256) {
    int s = q/96, f4 = q%96;
    *(float4*)&Vs[s*388 + f4*4] = *((const float4*)(V + (size_t)(bn*32+s)*9216 + jc*384) + f4);
  }
  __syncthreads();
  int tq = tid>>5, ec = tid&31;
  float4 acc[4][3];
  #pragma unroll
  for (int a=0;a<4;a++)
    #pragma unroll
    for (int c=0;c<3;c++) acc[a][c] = make_float4(0.f,0.f,0.f,0.f);
  for (int s=0; s<32; ++s) {
    float sc[4];
    #pragma unroll
    for (int a=0;a<4;a++) sc[a] = scs[(tq*4+a)*33 + s];
    #pragma unroll
    for (int cc=0;cc<3;cc++){
      float4 v = *(float4*)&Vs[s*388 + (ec+32*cc)*4];
      #pragma unroll
      for (int a=0;a<4;a++){
        acc[a][cc].x += sc[a]*v.x; acc[a][cc].y += sc[a]*v.y;
        acc[a][cc].z += sc[a]*v.z; acc[a][cc].w += sc[a]*v.w;
      }
    }
  }
  #pragma unroll
  for (int a=0;a<4;a++)
    #pragma unroll
    for (int cc=0;cc<3;cc++)
      *((float4*)(O + (size_t)(bn*32 + tq*4+a)*9216 + jc*384) + (ec+32*cc)) = acc[a][cc];
}

// ---------------- K5: inverse DFT + gauss + write out ----------------
// grid (idx, half, rnd): 2048 blocks, 512 thr. Fs read direct from global
// (per-wave 512B contiguous, 8x reuse via L1/L2). LDS 24.8KB -> 4 blocks/CU.
__global__ __launch_bounds__(512) void k5_out(const float* __restrict__ ws, float* __restrict__ dout) {
  __shared__ float Cs[6144];     // [hl(16)][col(192)][2], wgt/2048 folded
  __shared__ float gt[64];       // unnormalized gaussian
  int tid = threadIdx.x;
  int idx  = blockIdx.x;         // bn*32 + t
  int half = blockIdx.y;
  int rnd  = blockIdx.z;
  if (tid < 64) { float dr = tid - 31.5f; gt[tid] = expf(-0.02f*dr*dr); }
  __syncthreads();
  float gsum = 0.f;
  for (int i=0;i<64;i++) gsum += gt[i];    // same order as before -> same rounding
  const float* src = ws + (half ? SZ_Q : 0ull) + (size_t)idx*9216;
  { // stage A: kh-sum for 16 h rows, e^{+2pi i kh h/32} via recurrence
    int h2 = tid>>6, cg = tid&63;
    int h0 = rnd*16 + h2*2, h1 = h0+1;
    float s0,c0s,s1,c1s;
    sincosf((PI2/32.f)*h0, &s0, &c0s);
    sincosf((PI2/32.f)*h1, &s1, &c1s);
    float e0r=1.f, e0i=0.f, e1r=1.f, e1i=0.f;
    float a0r[3]={0},a0i[3]={0},a1r[3]={0},a1i[3]={0};
    const float2* sp = (const float2*)src;
    for (int ki=0; ki<24; ++ki) {
      if (ki==12) {
        float s,c;
        sincosf((PI2/32.f)*((20*h0)&31), &s, &c); e0r=c; e0i=s;
        sincosf((PI2/32.f)*((20*h1)&31), &s, &c); e1r=c; e1i=s;
      }
      #pragma unroll
      for (int k=0;k<3;k++){
        float2 f = sp[ki*192 + cg + 64*k];
        a0r[k] += f.x*e0r - f.y*e0i;  a0i[k] += f.x*e0i + f.y*e0r;
        a1r[k] += f.x*e1r - f.y*e1i;  a1i[k] += f.x*e1i + f.y*e1r;
      }
      float n0r = e0r*c0s - e0i*s0, n0i = e0r*s0 + e0i*c0s; e0r=n0r; e0i=n0i;
      float n1r = e1r*c1s - e1i*s1, n1i = e1r*s1 + e1i*c1s; e1r=n1r; e1i=n1i;
    }
    #pragma unroll
    for (int k=0;k<3;k++){
      int col = cg+64*k, kw = col>>4;
      float sc = (kw==0 ? 1.f : 2.f) * (1.f/2048.f);
      int base0 = (h2*2*192 + col)*2;
      Cs[base0]     = a0r[k]*sc; Cs[base0+1]   = a0i[k]*sc;
      Cs[base0+384] = a1r[k]*sc; Cs[base0+385] = a1i[k]*sc;
    }
  }
  __syncthreads();
  { // stage B: kw-sum over w with phi recurrence, gauss, store
    int hl = tid>>5, wg = (tid>>2)&7, dq = tid&3;
    float cr[12][4], ci[12][4];
    #pragma unroll
    for (int kw=0;kw<12;kw++){
      float4 u = *(float4*)&Cs[hl*384 + kw*32 + dq*8];
      float4 v = *(float4*)&Cs[hl*384 + kw*32 + dq*8 + 4];
      cr[kw][0]=u.x; ci[kw][0]=u.y; cr[kw][1]=u.z; ci[kw][1]=u.w;
      cr[kw][2]=v.x; ci[kw][2]=v.y; cr[kw][3]=v.z; ci[kw][3]=v.w;
    }
    int row = half*32 + rnd*16 + hl;
    float grow = gt[row]/gsum;          // == normalized gt[row] (same rounding)
    float pr, pi;
    sincosf((PI2/64.f)*wg, &pi, &pr);   // phi = e^{2pi i w/64}
    float* ob = dout + (size_t)idx*65536 + (size_t)row*1024;
    for (int k=0;k<8;k++){
      int w = wg + 8*k;
      float v0=cr[0][0], v1=cr[0][1], v2=cr[0][2], v3=cr[0][3];
      float tr=pr, ti=pi;
      #pragma unroll
      for (int kw=1;kw<12;kw++){
        v0 += cr[kw][0]*tr - ci[kw][0]*ti;
        v1 += cr[kw][1]*tr - ci[kw][1]*ti;
        v2 += cr[kw][2]*tr - ci[kw][2]*ti;
        v3 += cr[kw][3]*tr - ci[kw][3]*ti;
        float nr = tr*pr - ti*pi, ni = tr*pi + ti*pr;
        tr=nr; ti=ni;
      }
      float g = grow * (gt[w]/gsum);    // == grow * normalized gt[w]
      *(float4*)(ob + w*16 + dq*4) = make_float4(v0*g, v1*g, v2*g, v3*g);
      float nr = (pr - pi)*0.70710678118654752f;  // phi *= e^{i pi/4}  (w += 8)
      float ni = (pr + pi)*0.70710678118654752f;
      pr=nr; pi=ni;
    }
  }
}

extern "C" void kernel_launch(void* const* d_in, const int* in_sizes, int n_in,
                              void* d_out, int out_size, void* d_ws, size_t ws_size,
                              hipStream_t stream) {
  const float* z   = (const float*)d_in[0];
  const float* wq  = (const float*)d_in[1];
  const float* wk  = (const float*)d_in[2];
  const float* wvx = (const float*)d_in[3];
  const float* wvy = (const float*)d_in[4];
  float* out = (float*)d_out;
  float* ws  = (float*)d_ws;
  hipLaunchKernelGGL(k0_repack, dim3(576,4), dim3(256), 0, stream, wq, wk, wvx, wvy, out);
  hipLaunchKernelGGL(k1a_dftw,  dim3(1024),  dim3(256), 0, stream, z, ws);
  hipLaunchKernelGGL(k1b_dfth,  dim3(1024),  dim3(256), 0, stream, ws);
  hipLaunchKernelGGL(k2_wmul,   dim3(288,4,2), dim3(256), 0, stream, ws, out);
  hipLaunchKernelGGL(k3_scores, dim3(48,16), dim3(256), 0, stream, out);
  hipLaunchKernelGGL(k3b_reduce,dim3(16),    dim3(256), 0, stream, out);
  hipLaunchKernelGGL(k4_mix,    dim3(24,16,2), dim3(256), 0, stream, out, ws);
  hipLaunchKernelGGL(k5_out,    dim3(512,2,2), dim3(512), 0, stream, ws, out);
}

// Round 6
// 509.440 us; speedup vs baseline: 1.1345x; 1.0729x over previous
//
#include <hip/hip_runtime.h>
#include <math.h>

#define PI2 6.283185307179586f

typedef float f2v __attribute__((ext_vector_type(2)));

// dims: B=4 T=32 C=64 NHEAD=4 DK=16, modes: kh 24 (0..11,20..31), kw 12, J=288
#define SZ_U  (128ull*64*12*64*2)        // 12,582,912 floats  ws[0..)
#define OFF_X (SZ_U)                     // XYft 9,437,184 floats
#define SZ_Q  (4ull*4*32*288*16*2)       // 4,718,592 floats per tensor
// d_out float offsets (scratch staged in d_out; K5 overwrites everything)
#define DO_WP (4ull*SZ_Q)                // Wpack 9,437,184
#define DO_P  (DO_WP + 9437184ull)       // partial scores 786,432
#define DO_S  (DO_P + 786432ull)         // scores 16,384
#define C0f   5.9604644775390625e-8f     // 2^-24

// ---------------- K0: repack weights -> Wpack[tau][j][ri][i][on] ----------------
__global__ __launch_bounds__(256) void k0_repack(
    const float* __restrict__ wq, const float* __restrict__ wk,
    const float* __restrict__ wvx, const float* __restrict__ wvy,
    float* __restrict__ dout) {
  const float* src = (blockIdx.y==0)?wq:(blockIdx.y==1)?wk:(blockIdx.y==2)?wvx:wvy;
  float* wp = dout + DO_WP;
  int base = (blockIdx.x*256 + threadIdx.x)*4;
  #pragma unroll
  for (int u=0; u<4; ++u) {
    int s4 = base + u;
    int m2 = s4 % 12;  int r1 = s4/12;
    int m1 = r1 % 12;  int r2 = r1/12;
    int o  = r2 % 16;  int r3 = r2/16;
    int i  = r3 & 63;  int r4 = r3 >> 6;
    int ri = r4 & 1;   int p  = r4 >> 1;
    int j  = (p*12 + m1)*12 + m2;
    float4 v = ((const float4*)src)[s4];
    size_t d4 = ((size_t)(blockIdx.y*288 + j)*2 + ri)*1024 + (size_t)i*16 + o;
    ((float4*)wp)[d4] = v;
  }
}

// ---------------- K1a: w-DFT (64 -> 12 modes), twiddle recurrence in regs ----------------
__global__ __launch_bounds__(256) void k1a_dftw(const float* __restrict__ z, float* __restrict__ ws) {
  float* U = ws;  // U[bt][r][kw][c][2]
  int tid = threadIdx.x;
  int c4 = tid & 15, kg = (tid>>4)&3, rsub = tid>>6;
  int bt = blockIdx.x >> 3, rg = blockIdx.x & 7;
  float ck[3], sk[3];
  #pragma unroll
  for (int kk=0; kk<3; ++kk) { float s,c; sincosf((PI2/64.f)*(kg+4*kk), &s, &c); ck[kk]=c; sk[kk]=s; }
  for (int it=0; it<2; ++it) {
    int r = rg*8 + it*4 + rsub;
    const float4* zr = (const float4*)(z + ((size_t)bt*64 + r)*4096) + c4;
    float ar[3][4]={{0}}, ai[3][4]={{0}};
    float tr[3]={1.f,1.f,1.f}, ti[3]={0.f,0.f,0.f};
    #pragma unroll 8
    for (int w=0; w<64; ++w) {
      float4 x = zr[(size_t)w*16];
      #pragma unroll
      for (int kk=0; kk<3; ++kk) {
        ar[kk][0] += x.x*tr[kk]; ai[kk][0] += x.x*ti[kk];
        ar[kk][1] += x.y*tr[kk]; ai[kk][1] += x.y*ti[kk];
        ar[kk][2] += x.z*tr[kk]; ai[kk][2] += x.z*ti[kk];
        ar[kk][3] += x.w*tr[kk]; ai[kk][3] += x.w*ti[kk];
        float nr = tr[kk]*ck[kk] + ti[kk]*sk[kk];   // tw *= e^{-2pi i kw/64}
        float ni = ti[kk]*ck[kk] - tr[kk]*sk[kk];
        tr[kk]=nr; ti[kk]=ni;
      }
    }
    #pragma unroll
    for (int kk=0; kk<3; ++kk) {
      int kw = kg+4*kk;
      float4* up = (float4*)(U + (((size_t)bt*64 + r)*12 + kw)*128 + c4*8);
      up[0] = make_float4(ar[kk][0],ai[kk][0],ar[kk][1],ai[kk][1]);
      up[1] = make_float4(ar[kk][2],ai[kk][2],ar[kk][3],ai[kk][3]);
    }
  }
}

// ---------------- K1b: h-DFT (32 -> 24 modes) ----------------
__global__ __launch_bounds__(256) void k1b_dfth(float* __restrict__ ws) {
  const float* U = ws;
  float* X = ws + OFF_X;                // X[bt][half][j][c][2]
  __shared__ float Et[768*2];           // [h][ki] e^{-2pi i kh h/32}
  __shared__ float Ut[32*192*2];        // [h][col=kw*16+cc][2]
  int tid = threadIdx.x;
  for (int q = tid; q < 768; q += 256) {
    int h = q/24, ki = q%24;
    int kh = ki<12 ? ki : ki+8;
    float s,c; sincosf((PI2/32.f)*((kh*h)&31), &s, &c);
    Et[q*2] = c; Et[q*2+1] = -s;
  }
  int bt = blockIdx.x>>3, half = (blockIdx.x>>2)&1, c0 = (blockIdx.x&3)*16;
  for (int q = tid; q < 6144; q += 256) {
    int h = q/192, col = q%192, kw = col>>4, cc = col&15;
    ((float2*)Ut)[q] = *((const float2*)(U + (((size_t)bt*64 + half*32 + h)*12 + kw)*128) + (c0+cc));
  }
  __syncthreads();
  int k3 = tid>>5, cg = tid&31;
  float vr[3][6]={{0}}, vi[3][6]={{0}};
  for (int h=0; h<32; ++h) {
    float er[3], ei[3];
    #pragma unroll
    for (int a=0;a<3;a++){ int ki=k3*3+a; er[a]=Et[(h*24+ki)*2]; ei[a]=Et[(h*24+ki)*2+1]; }
    #pragma unroll
    for (int k=0;k<6;k++){
      float2 u = *(float2*)&Ut[(h*192 + cg + 32*k)*2];
      #pragma unroll
      for (int a=0;a<3;a++){
        vr[a][k] += u.x*er[a] - u.y*ei[a];
        vi[a][k] += u.y*er[a] + u.x*ei[a];
      }
    }
  }
  #pragma unroll
  for (int a=0;a<3;a++)
    #pragma unroll
    for (int k=0;k<6;k++){
      int col = cg+32*k, kw = col>>4, cc = col&15, ki = k3*3+a, j = ki*12+kw;
      *(float2*)(X + ((size_t)(bt*2+half)*288 + j)*128 + (size_t)(c0+cc)*2) = make_float2(vr[a][k], vi[a][k]);
    }
}

// ---------------- K2: per-mode complex GEMM  Q[bt][o,n] = sum_i X[bt][i]*W[i][o,n] ----------------
// grid (288 j, 4 tau, 2 btc) = 2304 uniform blocks, reg-prefetch pipeline.
// Inner loop: packed complex MAC via v_pk_fma_f32 (ext_vector f2v).
__global__ __launch_bounds__(256,3) void k2_wmul(const float* __restrict__ ws, float* __restrict__ dout) {
  const float* X = ws + OFF_X;
  const float* Wp = dout + DO_WP;
  __shared__ float Xs[64*132];   // [btL][c][2], row stride 132 floats (pad 4)
  __shared__ float Ws[32*128];   // half-K: [i32][p][2], p = o+16n
  int j = blockIdx.x, tau = blockIdx.y, btc = blockIdx.z;
  int half = (tau==3) ? 1 : 0;
  int tid = threadIdx.x;
  const float4* wsrc = (const float4*)(Wp + ((size_t)(tau*288 + j))*8192);
  // prefetch W(kh=0) -> regs
  float4 wa0[2], wb0[2];
  #pragma unroll
  for (int u=0;u<2;++u){ wa0[u]=wsrc[tid+256*u]; wb0[u]=wsrc[1024+tid+256*u]; }
  // stage X (full K) while W0 is in flight
  for (int q = tid; q < 2048; q += 256) {
    int btL = q>>5, c4 = q&31;
    float4 v = *((const float4*)(X + ((size_t)((btc*64+btL)*2 + half)*288 + j)*128) + c4);
    *(float4*)&Xs[btL*132 + c4*4] = v;
  }
  // write Ws(kh=0)
  #pragma unroll
  for (int u=0;u<2;++u){
    int q = tid+256*u; int i32 = q>>4, o = q&15;
    float* wd = &Ws[i32*128 + o*2];
    *(float2*)&wd[0]  = make_float2(wa0[u].x, wb0[u].x);
    *(float2*)&wd[32] = make_float2(wa0[u].y, wb0[u].y);
    *(float2*)&wd[64] = make_float2(wa0[u].z, wb0[u].z);
    *(float2*)&wd[96] = make_float2(wa0[u].w, wb0[u].w);
  }
  // prefetch W(kh=1) -> regs; latency hides under compute(kh=0)
  float4 wa1[2], wb1[2];
  #pragma unroll
  for (int u=0;u<2;++u){ wa1[u]=wsrc[512+tid+256*u]; wb1[u]=wsrc[1536+tid+256*u]; }
  int trow = tid>>4, tcol = tid&15;
  f2v acc[4][4];
  #pragma unroll
  for (int a=0;a<4;a++)
    #pragma unroll
    for (int b=0;b<4;b++) acc[a][b] = (f2v){0.f, 0.f};
  __syncthreads();
  { // compute kh=0
    const float* xb = &Xs[trow*132];
    const f2v*  wb2 = (const f2v*)&Ws[tcol*2];   // wb2[i*64 + b*16]
    #pragma unroll 8
    for (int ip=0; ip<16; ++ip) {
      float4 xq[4];
      #pragma unroll
      for (int a=0;a<4;a++) xq[a] = *(const float4*)&xb[a*2112 + ip*4];
      f2v wp0[4], wp1[4];
      #pragma unroll
      for (int b=0;b<4;b++){ wp0[b] = wb2[(2*ip)*64 + b*16]; wp1[b] = wb2[(2*ip+1)*64 + b*16]; }
      #pragma unroll
      for (int a=0;a<4;a++){
        f2v xr0 = (f2v){ xq[a].x, xq[a].x};
        f2v xi0 = (f2v){-xq[a].y, xq[a].y};
        f2v xr1 = (f2v){ xq[a].z, xq[a].z};
        f2v xi1 = (f2v){-xq[a].w, xq[a].w};
        #pragma unroll
        for (int b=0;b<4;b++){
          acc[a][b] = __builtin_elementwise_fma(xr0, wp0[b],    acc[a][b]);
          acc[a][b] = __builtin_elementwise_fma(xi0, wp0[b].yx, acc[a][b]);
          acc[a][b] = __builtin_elementwise_fma(xr1, wp1[b],    acc[a][b]);
          acc[a][b] = __builtin_elementwise_fma(xi1, wp1[b].yx, acc[a][b]);
        }
      }
    }
  }
  __syncthreads();
  // write Ws(kh=1) from regs
  #pragma unroll
  for (int u=0;u<2;++u){
    int q = tid+256*u; int i32 = q>>4, o = q&15;
    float* wd = &Ws[i32*128 + o*2];
    *(float2*)&wd[0]  = make_float2(wa1[u].x, wb1[u].x);
    *(float2*)&wd[32] = make_float2(wa1[u].y, wb1[u].y);
    *(float2*)&wd[64] = make_float2(wa1[u].z, wb1[u].z);
    *(float2*)&wd[96] = make_float2(wa1[u].w, wb1[u].w);
  }
  __syncthreads();
  { // compute kh=1
    const float* xb = &Xs[trow*132 + 64];
    const f2v*  wb2 = (const f2v*)&Ws[tcol*2];
    #pragma unroll 8
    for (int ip=0; ip<16; ++ip) {
      float4 xq[4];
      #pragma unroll
      for (int a=0;a<4;a++) xq[a] = *(const float4*)&xb[a*2112 + ip*4];
      f2v wp0[4], wp1[4];
      #pragma unroll
      for (int b=0;b<4;b++){ wp0[b] = wb2[(2*ip)*64 + b*16]; wp1[b] = wb2[(2*ip+1)*64 + b*16]; }
      #pragma unroll
      for (int a=0;a<4;a++){
        f2v xr0 = (f2v){ xq[a].x, xq[a].x};
        f2v xi0 = (f2v){-xq[a].y, xq[a].y};
        f2v xr1 = (f2v){ xq[a].z, xq[a].z};
        f2v xi1 = (f2v){-xq[a].w, xq[a].w};
        #pragma unroll
        for (int b=0;b<4;b++){
          acc[a][b] = __builtin_elementwise_fma(xr0, wp0[b],    acc[a][b]);
          acc[a][b] = __builtin_elementwise_fma(xi0, wp0[b].yx, acc[a][b]);
          acc[a][b] = __builtin_elementwise_fma(xr1, wp1[b],    acc[a][b]);
          acc[a][b] = __builtin_elementwise_fma(xi1, wp1[b].yx, acc[a][b]);
        }
      }
    }
  }
  float* obase = dout + (size_t)tau*SZ_Q;
  #pragma unroll
  for (int a=0;a<4;a++){
    int bt = btc*64 + trow + 16*a;
    int b_ = bt>>5, t = bt&31;
    #pragma unroll
    for (int bb=0;bb<4;bb++){
      int o = tcol, n = bb;   // lane-contiguous 128B per (row) chunk
      *(f2v*)(obase + ((((size_t)(b_*4+n)*32 + t)*288 + j)*16 + o)*2) = acc[a][bb];
    }
  }
}

// ---------------- K3: partial scores in mode space (Gram with kw=0 conj-partner fix) ----------------
__global__ __launch_bounds__(256) void k3_scores(float* __restrict__ dout) {
  const float* Q = dout;
  const float* K = dout + SZ_Q;
  float* P = dout + DO_P;
  __shared__ float lds[12544];
  float* Qs = lds;            // 32 rows * 196
  float* Ks = lds + 6272;
  int jc = blockIdx.x, bn = blockIdx.y;
  int tid = threadIdx.x;
  for (int q = tid; q < 1536; q += 256) {
    int t = q/48, f4 = q%48;
    *(float4*)&Qs[t*196 + f4*4] = *((const float4*)(Q + (size_t)(bn*32+t)*9216 + jc*192) + f4);
  }
  for (int q = tid; q < 1536; q += 256) {
    int s = q/48, f4 = q%48;
    int kw = (jc*6 + (f4>>3)) % 12;
    float w1 = (kw==0) ? C0f : 4.f*C0f;
    float4 v = *((const float4*)(K + (size_t)(bn*32+s)*9216 + jc*192) + f4);
    v.x*=w1; v.y*=w1; v.z*=w1; v.w*=w1;
    *(float4*)&Ks[s*196 + f4*4] = v;
  }
  __syncthreads();
  if (((jc&1)==0) && ((jc>>1)!=12)) {           // kw==0 column lives at local j 0 when jc even
    int khI = jc>>1;
    int jp = ((24 - khI) % 24) * 12;            // conjugate partner mode
    for (int q = tid; q < 512; q += 256) {
      int s = q>>4, d = q&15;
      float2 kp = *((const float2*)(K + (size_t)(bn*32+s)*9216 + (size_t)jp*32) + d);
      Ks[s*196 + d*2]     += C0f * kp.x;
      Ks[s*196 + d*2 + 1] -= C0f * kp.y;
    }
  }
  __syncthreads();
  int tq = tid>>5, sq = (tid>>2)&7, eg = tid&3;
  float acc[4][4]={{0}};
  for (int e=0; e<12; ++e) {
    float4 qv[4], kv[4];
    #pragma unroll
    for (int a=0;a<4;a++) qv[a] = *(float4*)&Qs[(tq*4+a)*196 + eg*48 + e*4];
    #pragma unroll
    for (int b=0;b<4;b++) kv[b] = *(float4*)&Ks[(sq*4+b)*196 + eg*48 + e*4];
    #pragma unroll
    for (int a=0;a<4;a++)
      #pragma unroll
      for (int b=0;b<4;b++)
        acc[a][b] += qv[a].x*kv[b].x + qv[a].y*kv[b].y + qv[a].z*kv[b].z + qv[a].w*kv[b].w;
  }
  __syncthreads();
  float* Pp = lds;            // alias (Qs dead)
  #pragma unroll
  for (int a=0;a<4;a++)
    #pragma unroll
    for (int b=0;b<4;b++)
      Pp[eg*1056 + (tq*4+a)*33 + (sq*4+b)] = acc[a][b];
  __syncthreads();
  for (int q = tid; q < 1024; q += 256) {
    int t = q>>5, s = q&31;
    float r = Pp[t*33+s] + Pp[1056 + t*33+s] + Pp[2112 + t*33+s] + Pp[3168 + t*33+s];
    P[(size_t)(jc*16 + bn)*1024 + q] = r;
  }
}

__global__ __launch_bounds__(256) void k3b_reduce(float* __restrict__ dout) {
  const float* P = dout + DO_P;
  float* S = dout + DO_S;
  int bn = blockIdx.x, tid = threadIdx.x;
  for (int q = tid; q < 1024; q += 256) {
    float a = 0.f;
    for (int jc=0; jc<48; ++jc) a += P[(size_t)(jc*16+bn)*1024 + q];
    S[bn*1024 + q] = a;
  }
}

// ---------------- K4: mode-space score mixing  O[t] = sum_s S[t][s] V[s] ----------------
__global__ __launch_bounds__(256) void k4_mix(const float* __restrict__ dout, float* __restrict__ ws) {
  const float* S = dout + DO_S;
  const float* V = dout + (blockIdx.z==0 ? 2ull*SZ_Q : 3ull*SZ_Q);
  float* O = ws + (blockIdx.z==0 ? 0ull : SZ_Q);    // aliases dead U region
  __shared__ float scs[1056];
  __shared__ float Vs[32*388];
  int jc = blockIdx.x, bn = blockIdx.y, tid = threadIdx.x;
  for (int q = tid; q < 1024; q += 256) scs[(q>>5)*33 + (q&31)] = S[bn*1024 + q];
  for (int q = tid; q < 3072; q += 256) {
    int s = q/96, f4 = q%96;
    *(float4*)&Vs[s*388 + f4*4] = *((const float4*)(V + (size_t)(bn*32+s)*9216 + jc*384) + f4);
  }
  __syncthreads();
  int tq = tid>>5, ec = tid&31;
  float4 acc[4][3];
  #pragma unroll
  for (int a=0;a<4;a++)
    #pragma unroll
    for (int c=0;c<3;c++) acc[a][c] = make_float4(0.f,0.f,0.f,0.f);
  for (int s=0; s<32; ++s) {
    float sc[4];
    #pragma unroll
    for (int a=0;a<4;a++) sc[a] = scs[(tq*4+a)*33 + s];
    #pragma unroll
    for (int cc=0;cc<3;cc++){
      float4 v = *(float4*)&Vs[s*388 + (ec+32*cc)*4];
      #pragma unroll
      for (int a=0;a<4;a++){
        acc[a][cc].x += sc[a]*v.x; acc[a][cc].y += sc[a]*v.y;
        acc[a][cc].z += sc[a]*v.z; acc[a][cc].w += sc[a]*v.w;
      }
    }
  }
  #pragma unroll
  for (int a=0;a<4;a++)
    #pragma unroll
    for (int cc=0;cc<3;cc++)
      *((float4*)(O + (size_t)(bn*32 + tq*4+a)*9216 + jc*384) + (ec+32*cc)) = acc[a][cc];
}

// ---------------- K5: inverse DFT + gauss + write out ----------------
// grid (idx, half, rnd): 2048 blocks, 512 thr. 25KB LDS.
// Stage A/B use packed complex math (v_pk_fma_f32); stage B additionally uses
// the w/w+32 butterfly: phi_{w+32} = -phi_w so even/odd-kw partial sums give
// v_w = E+O and v_{w+32} = E-O from one 12-kw sweep (halves FMA + twiddles).
__global__ __launch_bounds__(512) void k5_out(const float* __restrict__ ws, float* __restrict__ dout) {
  __shared__ float Cs[6144];     // [hl(16)][col(192)][2], wgt/2048 folded
  __shared__ float gt[64];       // unnormalized gaussian
  int tid = threadIdx.x;
  int idx  = blockIdx.x;         // bn*32 + t
  int half = blockIdx.y;
  int rnd  = blockIdx.z;
  if (tid < 64) { float dr = tid - 31.5f; gt[tid] = expf(-0.02f*dr*dr); }
  __syncthreads();
  float gsum = 0.f;
  for (int i=0;i<64;i++) gsum += gt[i];    // same order as before -> same rounding
  const float* src = ws + (half ? SZ_Q : 0ull) + (size_t)idx*9216;
  { // stage A: kh-sum for 16 h rows, packed complex recurrence
    int h2 = tid>>6, cg = tid&63;
    int h0 = rnd*16 + h2*2, h1 = h0+1;
    float s0,c0s,s1,c1s;
    sincosf((PI2/32.f)*h0, &s0, &c0s);
    sincosf((PI2/32.f)*h1, &s1, &c1s);
    f2v cs0 = {c0s, s0}, cs1 = {c1s, s1};
    f2v e0 = {1.f, 0.f}, e1 = {1.f, 0.f};
    f2v a0[3] = {{0.f,0.f},{0.f,0.f},{0.f,0.f}};
    f2v a1[3] = {{0.f,0.f},{0.f,0.f},{0.f,0.f}};
    const f2v* sp = (const f2v*)src;
    for (int ki=0; ki<24; ++ki) {
      if (ki==12) {
        float s,c;
        sincosf((PI2/32.f)*((20*h0)&31), &s, &c); e0 = (f2v){c, s};
        sincosf((PI2/32.f)*((20*h1)&31), &s, &c); e1 = (f2v){c, s};
      }
      #pragma unroll
      for (int k=0;k<3;k++){
        f2v f = sp[ki*192 + cg + 64*k];
        f2v fx = {f.x, f.x}, fy = {-f.y, f.y};
        a0[k] = __builtin_elementwise_fma(fx, e0, a0[k]);
        a0[k] = __builtin_elementwise_fma(fy, e0.yx, a0[k]);
        a1[k] = __builtin_elementwise_fma(fx, e1, a1[k]);
        a1[k] = __builtin_elementwise_fma(fy, e1.yx, a1[k]);
      }
      e0 = __builtin_elementwise_fma((f2v){e0.x,e0.x}, cs0, (f2v){-e0.y,e0.y} * cs0.yx);
      e1 = __builtin_elementwise_fma((f2v){e1.x,e1.x}, cs1, (f2v){-e1.y,e1.y} * cs1.yx);
    }
    #pragma unroll
    for (int k=0;k<3;k++){
      int col = cg+64*k, kw = col>>4;
      float sc = (kw==0 ? 1.f : 2.f) * (1.f/2048.f);
      f2v scv = {sc, sc};
      int base0 = (h2*2*192 + col)*2;
      *(f2v*)&Cs[base0]       = a0[k]*scv;
      *(f2v*)&Cs[base0 + 384] = a1[k]*scv;
    }
  }
  __syncthreads();
  { // stage B: kw-sum, packed d-pairs + w/w+32 butterfly
    int hl = tid>>5, wg = (tid>>2)&7, dq = tid&3;
    f2v crv[12][2], civ[12][2];
    #pragma unroll
    for (int kw=0;kw<12;kw++){
      float4 u = *(float4*)&Cs[hl*384 + kw*32 + dq*8];
      float4 v = *(float4*)&Cs[hl*384 + kw*32 + dq*8 + 4];
      crv[kw][0] = (f2v){u.x, u.z}; civ[kw][0] = (f2v){u.y, u.w};
      crv[kw][1] = (f2v){v.x, v.z}; civ[kw][1] = (f2v){v.y, v.w};
    }
    int row = half*32 + rnd*16 + hl;
    float grow = gt[row]/gsum;
    float pr, pi;
    sincosf((PI2/64.f)*wg, &pi, &pr);   // phi = e^{2pi i w/64}
    f2v p = {pr, pi};
    float* ob = dout + (size_t)idx*65536 + (size_t)row*1024;
    for (int k=0;k<4;k++){
      int w = wg + 8*k;                 // also produces w+32
      f2v E0 = crv[0][0], E1 = crv[0][1];   // kw=0 term (even)
      f2v O0 = {0.f,0.f}, O1 = {0.f,0.f};
      f2v t = p;
      #pragma unroll
      for (int kw=1;kw<12;kw++){
        f2v txx = {t.x, t.x}, tyy = {-t.y, -t.y};
        if (kw & 1) {
          O0 = __builtin_elementwise_fma(txx, crv[kw][0], O0);
          O0 = __builtin_elementwise_fma(tyy, civ[kw][0], O0);
          O1 = __builtin_elementwise_fma(txx, crv[kw][1], O1);
          O1 = __builtin_elementwise_fma(tyy, civ[kw][1], O1);
        } else {
          E0 = __builtin_elementwise_fma(txx, crv[kw][0], E0);
          E0 = __builtin_elementwise_fma(tyy, civ[kw][0], E0);
          E1 = __builtin_elementwise_fma(txx, crv[kw][1], E1);
          E1 = __builtin_elementwise_fma(tyy, civ[kw][1], E1);
        }
        t = __builtin_elementwise_fma((f2v){t.x,t.x}, p, (f2v){-t.y,t.y} * p.yx);
      }
      float gA = grow * (gt[w]/gsum);
      float gB = grow * (gt[w+32]/gsum);
      f2v vA0 = (E0+O0), vA1 = (E1+O1);
      f2v vB0 = (E0-O0), vB1 = (E1-O1);
      *(float4*)(ob + w*16 + dq*4)      = make_float4(vA0.x*gA, vA0.y*gA, vA1.x*gA, vA1.y*gA);
      *(float4*)(ob + (w+32)*16 + dq*4) = make_float4(vB0.x*gB, vB0.y*gB, vB1.x*gB, vB1.y*gB);
      float nr = (p.x - p.y)*0.70710678118654752f;  // phi *= e^{i pi/4}  (w += 8)
      float ni = (p.x + p.y)*0.70710678118654752f;
      p = (f2v){nr, ni};
    }
  }
}

extern "C" void kernel_launch(void* const* d_in, const int* in_sizes, int n_in,
                              void* d_out, int out_size, void* d_ws, size_t ws_size,
                              hipStream_t stream) {
  const float* z   = (const float*)d_in[0];
  const float* wq  = (const float*)d_in[1];
  const float* wk  = (const float*)d_in[2];
  const float* wvx = (const float*)d_in[3];
  const float* wvy = (const float*)d_in[4];
  float* out = (float*)d_out;
  float* ws  = (float*)d_ws;
  hipLaunchKernelGGL(k0_repack, dim3(576,4), dim3(256), 0, stream, wq, wk, wvx, wvy, out);
  hipLaunchKernelGGL(k1a_dftw,  dim3(1024),  dim3(256), 0, stream, z, ws);
  hipLaunchKernelGGL(k1b_dfth,  dim3(1024),  dim3(256), 0, stream, ws);
  hipLaunchKernelGGL(k2_wmul,   dim3(288,4,2), dim3(256), 0, stream, ws, out);
  hipLaunchKernelGGL(k3_scores, dim3(48,16), dim3(256), 0, stream, out);
  hipLaunchKernelGGL(k3b_reduce,dim3(16),    dim3(256), 0, stream, out);
  hipLaunchKernelGGL(k4_mix,    dim3(24,16,2), dim3(256), 0, stream, out, ws);
  hipLaunchKernelGGL(k5_out,    dim3(512,2,2), dim3(512), 0, stream, ws, out);
}